// Round 1
// baseline (1958.910 us; speedup 1.0000x reference)
//
#include <hip/hip_runtime.h>
#include <math.h>
#include <stdint.h>

// ---------------- problem constants ----------------
#define T_STEPS 100
#define BATCH   128
#define EMB     64
#define RDIM    32
#define SDIM    32
#define INDIM   128          // EMB+RDIM+SDIM
#define HDIM    512
#define G4      2048         // 4*HDIM
#define ITEMS   10000
#define NPAD    10112        // 79*128 (N padded to tile multiple)
#define TBROWS  12800        // T*B
#define KLIN    544          // HDIM + SDIM

typedef unsigned short u16;
typedef __attribute__((ext_vector_type(8))) short  bf16x8;  // 8 bf16 (4 VGPRs)
typedef __attribute__((ext_vector_type(4))) float  f32x4;

__device__ __forceinline__ u16 f2bf(float x) {
  unsigned u = __float_as_uint(x);
  u = u + 0x7fffu + ((u >> 16) & 1u);   // RNE
  return (u16)(u >> 16);
}
__device__ __forceinline__ float bf2f(u16 b) { return __uint_as_float(((unsigned)b) << 16); }

// ---------------- workspace layout (bytes) ----------------
// total ~83.6 MB
#define OFF_SYNC   0UL          // 64 uints barrier counters @0, 2 float sumsq @256
#define OFF_XPROJ  512UL        // bf16 [12800][2048]                = 52,428,800
#define OFF_LININ  52429312UL   // bf16 [12800][544] (h | stat)      = 13,926,400
#define OFF_WLIN   66355712UL   // bf16 [10112][544]                 = 11,001,856
#define OFF_WHH    77357568UL   // bf16 [2048][512]  gate-interleaved=  2,097,152
#define OFF_WIH    79454720UL   // bf16 [2048][128]  gate-interleaved=    524,288
#define OFF_ARS    79979008UL   // bf16 [12800][128]                 =  3,276,800
#define OFF_BIAS   83255808UL   // f32  [2048] (b_ih+b_hh, permuted) =      8,192
#define OFF_HBUF   83264000UL   // bf16 2 x [4][32][552] dbl-buffer  =    282,624

#define HS    552               // padded h row stride (elems); 552*2=1104B -> 4-way max on b128
#define HSLAB 17664             // 32*HS elems per rb slice
#define HBUFE 70656             // 4*HSLAB elems per buffer

// ---------------- prep: casts, permutes, gather, l2 partials ----------------
__global__ void prep_kernel(const int* __restrict__ pa, const float* __restrict__ pr,
                            const float* __restrict__ ps, const float* __restrict__ hx,
                            const float* __restrict__ emb,
                            const float* __restrict__ W_ih, const float* __restrict__ W_hh,
                            const float* __restrict__ b_ih, const float* __restrict__ b_hh,
                            const float* __restrict__ W_lin, const float* __restrict__ b_lin,
                            u16* __restrict__ ars, u16* __restrict__ lin_in,
                            u16* __restrict__ wlin, u16* __restrict__ whh, u16* __restrict__ wih,
                            float* __restrict__ bias2, u16* __restrict__ hbuf,
                            float* __restrict__ acc) {
  const int tid0 = blockIdx.x * blockDim.x + threadIdx.x;
  const int np = gridDim.x * blockDim.x;
  float sw = 0.f, sb = 0.f;
  // W_lin cast (+zero pad rows) + Frobenius partial
  for (int i = tid0; i < NPAD * KLIN; i += np) {
    int v = i / KLIN;
    float x = (v < ITEMS) ? W_lin[i] : 0.f;
    wlin[i] = f2bf(x);
    sw += x * x;
  }
  for (int i = tid0; i < ITEMS; i += np) { float x = b_lin[i]; sb += x * x; }
  // W_hh gate-interleaved rows: g' = 4*j + gate  <->  g = gate*512 + j
  for (int i = tid0; i < G4 * HDIM; i += np) {
    int gp = i >> 9, k = i & 511;
    int g = (gp & 3) * 512 + (gp >> 2);
    whh[i] = f2bf(W_hh[g * HDIM + k]);
  }
  for (int i = tid0; i < G4 * INDIM; i += np) {
    int gp = i >> 7, k = i & 127;
    int g = (gp & 3) * 512 + (gp >> 2);
    wih[i] = f2bf(W_ih[g * INDIM + k]);
  }
  for (int i = tid0; i < G4; i += np) {
    int g = (i & 3) * 512 + (i >> 2);
    bias2[i] = b_ih[g] + b_hh[g];
  }
  // ars = [emb | one_hot | stat], bf16
  for (int i = tid0; i < TBROWS * INDIM; i += np) {
    int tb = i >> 7, k = i & 127;
    float v;
    if (k < EMB) {
      v = emb[pa[tb] * EMB + k];
    } else if (k < EMB + RDIM) {
      int idx = (int)floorf((float)RDIM * (2.0f - pr[tb]) * 0.25f);  // == floor(RDIM*(2-r)/4)
      v = ((k - EMB) == idx) ? 1.0f : 0.0f;
    } else {
      v = ps[tb * SDIM + (k - EMB - RDIM)];
    }
    ars[i] = f2bf(v);
  }
  // lin_in statistic tail
  for (int i = tid0; i < TBROWS * SDIM; i += np) {
    int tb = i >> 5, s = i & 31;
    lin_in[(size_t)tb * KLIN + HDIM + s] = f2bf(ps[i]);
  }
  // h0 into padded double-buffer slot 0
  for (int i = tid0; i < BATCH * HDIM; i += np) {
    int b = i >> 9, k = i & 511;
    hbuf[(b >> 5) * HSLAB + (b & 31) * HS + k] = f2bf(hx[i]);
  }
  // reduce l2 partials: wave shuffle -> LDS -> 1 atomic/block
  __shared__ float red[2][8];
  for (int off = 32; off > 0; off >>= 1) { sw += __shfl_down(sw, off); sb += __shfl_down(sb, off); }
  int lane = threadIdx.x & 63, wv = threadIdx.x >> 6;
  if (lane == 0) { red[0][wv] = sw; red[1][wv] = sb; }
  __syncthreads();
  if (threadIdx.x == 0) {
    float a = 0.f, b = 0.f;
    for (int w = 0; w < (int)(blockDim.x >> 6); ++w) { a += red[0][w]; b += red[1][w]; }
    atomicAdd(&acc[0], a);
    atomicAdd(&acc[1], b);
  }
}

__global__ void l2_kernel(const float* __restrict__ acc, float* __restrict__ out) {
  out[0] = sqrtf(acc[0]) + sqrtf(acc[1]);
}

// ---------------- 128x128-tile bf16 MFMA GEMM, C = A * B^T (+bias) ----------------
// A [M x K] row-major bf16, B [N x K] row-major bf16, BK=32, 4 waves each 64x64.
// EPI=0: store bf16 to Cout[M][N] (xproj). EPI=1: store f32 with n<N bound (pn_outputs).
template <int EPI>
__global__ __launch_bounds__(256) void gemm_bt(const u16* __restrict__ A, const u16* __restrict__ Bm,
                                               const float* __restrict__ bias, void* __restrict__ Cout,
                                               int K, int N) {
  __shared__ u16 Asm[128 * 32];
  __shared__ u16 Bsm[128 * 32];
  const int tid = threadIdx.x;
  const int lane = tid & 63;
  const int wv = tid >> 6;
  const int wm = wv >> 1, wn = wv & 1;
  const int l15 = lane & 15, quad = lane >> 4;
  const int mt = blockIdx.y, nt = blockIdx.x;
  const u16* Ag = A + (size_t)mt * 128 * K;
  const u16* Bg = Bm + (size_t)nt * 128 * K;
  f32x4 acc[4][4] = {};

  for (int k0 = 0; k0 < K; k0 += 32) {
    __syncthreads();                     // previous iter's LDS reads done
    {
      int e = tid * 8;                   // elem offset in 128x32 tile (16B per thread)
      int row = e >> 5, col = e & 31;
      *(bf16x8*)&Asm[e]        = *(const bf16x8*)&Ag[(size_t)row * K + k0 + col];
      *(bf16x8*)&Asm[e + 2048] = *(const bf16x8*)&Ag[(size_t)(row + 64) * K + k0 + col];
      *(bf16x8*)&Bsm[e]        = *(const bf16x8*)&Bg[(size_t)row * K + k0 + col];
      *(bf16x8*)&Bsm[e + 2048] = *(const bf16x8*)&Bg[(size_t)(row + 64) * K + k0 + col];
    }
    __syncthreads();                     // staging visible
    bf16x8 af[4], bfr[4];
#pragma unroll
    for (int mi = 0; mi < 4; ++mi)
      af[mi] = *(const bf16x8*)&Asm[(wm * 64 + mi * 16 + l15) * 32 + quad * 8];
#pragma unroll
    for (int ni = 0; ni < 4; ++ni)
      bfr[ni] = *(const bf16x8*)&Bsm[(wn * 64 + ni * 16 + l15) * 32 + quad * 8];
#pragma unroll
    for (int mi = 0; mi < 4; ++mi)
#pragma unroll
      for (int ni = 0; ni < 4; ++ni)
        acc[mi][ni] = __builtin_amdgcn_mfma_f32_16x16x32_bf16(af[mi], bfr[ni], acc[mi][ni], 0, 0, 0);
  }
  // epilogue: C/D layout col=lane&15, row=quad*4+reg
#pragma unroll
  for (int mi = 0; mi < 4; ++mi) {
#pragma unroll
    for (int ni = 0; ni < 4; ++ni) {
      int ng = nt * 128 + wn * 64 + ni * 16 + l15;
      float bv = (EPI == 0 || ng < N) ? bias[ng] : 0.0f;
#pragma unroll
      for (int r = 0; r < 4; ++r) {
        int mg = mt * 128 + wm * 64 + mi * 16 + quad * 4 + r;
        float v = acc[mi][ni][r] + bv;
        if (EPI == 0) {
          ((u16*)Cout)[(size_t)mg * N + ng] = f2bf(v);
        } else {
          if (ng < N) ((float*)Cout)[(size_t)mg * (size_t)N + ng] = v;
        }
      }
    }
  }
}

// ---------------- LSTM scan: 64 WGs = 4 independent groups (32 batch rows each) ----------------
// Group grp owns batch rows [grp*32, grp*32+32). 16 WGs x 4 waves per group; wave -> 32-col
// (=8 j) slice of the gate-interleaved [32 x 2048] gates tile, via 2x2 of 16x16x32 MFMA.
__global__ __launch_bounds__(256) void lstm_kernel(const u16* __restrict__ xproj,
                                                   const u16* __restrict__ whh,
                                                   const float* __restrict__ cx,
                                                   u16* __restrict__ hbuf,
                                                   u16* __restrict__ lin_in,
                                                   unsigned* __restrict__ cnt) {
  __shared__ u16 hls[HSLAB];          // padded h slice [32][HS]
  __shared__ float gl[4][32 * 33];    // per-wave gates tile, +1 col pad
  const int tid = threadIdx.x;
  const int lane = tid & 63, wv = tid >> 6;
  const int wg = blockIdx.x;
  const int grp = wg >> 4;                   // batch row-block 0..3
  const int cb = (wg & 15) * 4 + wv;         // gate col-block 0..63 (32 g' = 8 j)
  const int l15 = lane & 15, quad = lane >> 4;
  const int lrow = lane & 31, lhalf = lane >> 5;
  const int b0 = grp * 32;
  const int bg = b0 + lrow;                  // owned batch row
  const int jbase = cb * 8 + lhalf * 4;      // owned j (4 consecutive)
  float c[4];
#pragma unroll
  for (int ii = 0; ii < 4; ++ii) c[ii] = cx[(size_t)bg * HDIM + jbase + ii];
  const u16* wpbase = whh + (size_t)(cb * 32) * HDIM;
  unsigned* mycnt = cnt + grp * 16;          // 64B-spaced per-group counters

  for (int t = 0; t < T_STEPS; ++t) {
    // stage this group's h slice (35,328 B) into LDS
    const u16* hsrc = hbuf + (size_t)(t & 1) * HBUFE + (size_t)grp * HSLAB;
    for (int s = tid; s < HSLAB / 8; s += 256)
      *(bf16x8*)&hls[s * 8] = *(const bf16x8*)&hsrc[s * 8];
    __syncthreads();

    // gates(32x32 slice) = h(32x512) * Whh'(32x512)^T via 2x2 16x16x32 tiles
    f32x4 acc[2][2] = {};
#pragma unroll 4
    for (int kk = 0; kk < 16; ++kk) {
      int kof = kk * 32 + quad * 8;
      bf16x8 a0 = *(const bf16x8*)&hls[l15 * HS + kof];
      bf16x8 a1 = *(const bf16x8*)&hls[(16 + l15) * HS + kof];
      bf16x8 bv0 = *(const bf16x8*)&wpbase[(size_t)l15 * HDIM + kof];
      bf16x8 bv1 = *(const bf16x8*)&wpbase[(size_t)(16 + l15) * HDIM + kof];
      acc[0][0] = __builtin_amdgcn_mfma_f32_16x16x32_bf16(a0, bv0, acc[0][0], 0, 0, 0);
      acc[0][1] = __builtin_amdgcn_mfma_f32_16x16x32_bf16(a0, bv1, acc[0][1], 0, 0, 0);
      acc[1][0] = __builtin_amdgcn_mfma_f32_16x16x32_bf16(a1, bv0, acc[1][0], 0, 0, 0);
      acc[1][1] = __builtin_amdgcn_mfma_f32_16x16x32_bf16(a1, bv1, acc[1][1], 0, 0, 0);
    }
    // + xproj, into LDS gates tile
    const u16* xp = xproj + (size_t)(t * BATCH + b0) * G4 + cb * 32;
    float* g_l = gl[wv];
#pragma unroll
    for (int sm = 0; sm < 2; ++sm)
#pragma unroll
      for (int sn = 0; sn < 2; ++sn)
#pragma unroll
        for (int r = 0; r < 4; ++r) {
          int m = sm * 16 + quad * 4 + r;
          int n = sn * 16 + l15;
          g_l[m * 33 + n] = acc[sm][sn][r] + bf2f(xp[(size_t)m * G4 + n]);
        }
    __syncthreads();   // cross-lane LDS visibility

    // elementwise: lane owns (b = b0+lrow, j = jbase..jbase+3)
    float hv[4];
#pragma unroll
    for (int ii = 0; ii < 4; ++ii) {
      int jl = lhalf * 4 + ii;
      float gi = g_l[lrow * 33 + jl * 4 + 0];
      float gf = g_l[lrow * 33 + jl * 4 + 1];
      float gg = g_l[lrow * 33 + jl * 4 + 2];
      float go = g_l[lrow * 33 + jl * 4 + 3];
      gi = 1.f / (1.f + __expf(-gi));
      gf = 1.f / (1.f + __expf(-gf));
      gg = 1.f - 2.f / (__expf(2.f * gg) + 1.f);   // tanh, inf-safe
      go = 1.f / (1.f + __expf(-go));
      float cn = gf * c[ii] + gi * gg;
      c[ii] = cn;
      hv[ii] = go * (1.f - 2.f / (__expf(2.f * cn) + 1.f));
    }
    uint2 pk;
    pk.x = (unsigned)f2bf(hv[0]) | ((unsigned)f2bf(hv[1]) << 16);
    pk.y = (unsigned)f2bf(hv[2]) | ((unsigned)f2bf(hv[3]) << 16);
    *(uint2*)&hbuf[(size_t)((t + 1) & 1) * HBUFE + (size_t)grp * HSLAB + lrow * HS + jbase] = pk;
    *(uint2*)&lin_in[(size_t)(t * BATCH + bg) * KLIN + jbase] = pk;

    // per-group barrier (monotonic counter, device-scope fences for cross-XCD h)
    __syncthreads();
    if (tid == 0) {
      __threadfence();
      atomicAdd(mycnt, 1u);
      const unsigned target = 16u * (unsigned)(t + 1);
      while (__hip_atomic_load(mycnt, __ATOMIC_ACQUIRE, __HIP_MEMORY_SCOPE_AGENT) < target)
        __builtin_amdgcn_s_sleep(1);
    }
    __syncthreads();
  }
}

// ---------------- launch ----------------
extern "C" void kernel_launch(void* const* d_in, const int* in_sizes, int n_in,
                              void* d_out, int out_size, void* d_ws, size_t ws_size,
                              hipStream_t stream) {
  const int*   pa   = (const int*)d_in[0];
  const float* pr   = (const float*)d_in[1];
  const float* ps   = (const float*)d_in[2];
  const float* hx   = (const float*)d_in[3];
  const float* cxp  = (const float*)d_in[4];
  const float* emb  = (const float*)d_in[5];
  const float* wih  = (const float*)d_in[6];
  const float* whh  = (const float*)d_in[7];
  const float* bih  = (const float*)d_in[8];
  const float* bhh  = (const float*)d_in[9];
  const float* wlin = (const float*)d_in[10];
  const float* blin = (const float*)d_in[11];

  char* ws = (char*)d_ws;
  unsigned* cnt   = (unsigned*)(ws + OFF_SYNC);
  float*    acc   = (float*)(ws + 256);
  u16* xprojW = (u16*)(ws + OFF_XPROJ);
  u16* lininW = (u16*)(ws + OFF_LININ);
  u16* wlinW  = (u16*)(ws + OFF_WLIN);
  u16* whhW   = (u16*)(ws + OFF_WHH);
  u16* wihW   = (u16*)(ws + OFF_WIH);
  u16* arsW   = (u16*)(ws + OFF_ARS);
  float* biasW = (float*)(ws + OFF_BIAS);
  u16* hbufW  = (u16*)(ws + OFF_HBUF);
  float* outF = (float*)d_out;

  hipMemsetAsync(d_ws, 0, 512, stream);  // barrier counters + l2 accumulators

  prep_kernel<<<dim3(2048), dim3(256), 0, stream>>>(
      pa, pr, ps, hx, emb, wih, whh, bih, bhh, wlin, blin,
      arsW, lininW, wlinW, whhW, wihW, biasW, hbufW, acc);

  l2_kernel<<<dim3(1), dim3(1), 0, stream>>>(acc, outF + (size_t)out_size - 1);

  // x_proj = ars * W_ih'^T + (b_ih+b_hh)   [12800 x 2048] bf16
  gemm_bt<0><<<dim3(16, 100), dim3(256), 0, stream>>>(arsW, wihW, biasW, (void*)xprojW, INDIM, G4);

  lstm_kernel<<<dim3(64), dim3(256), 0, stream>>>(xprojW, whhW, cxp, hbufW, lininW, cnt);

  // pn = lin_in * W_lin^T + b_lin          [12800 x 10000] f32
  gemm_bt<1><<<dim3(79, 100), dim3(256), 0, stream>>>(lininW, wlinW, blin, (void*)outF, KLIN, ITEMS);
}